// Round 2
// baseline (1398.456 us; speedup 1.0000x reference)
//
#include <hip/hip_runtime.h>
#include <hip/hip_bf16.h>
#include <math.h>

#define B_    16
#define L_    2048
#define H_    512
#define NT_   8
#define OUT_  1032
#define HEAD_ 256

__device__ __forceinline__ float b2f(unsigned short u) {
    union { unsigned int u32; float f; } v; v.u32 = ((unsigned int)u) << 16; return v.f;
}
__device__ __forceinline__ unsigned short f2b(float f) {
    __hip_bfloat16 h = __float2bfloat16(f);   // RNE
    return *reinterpret_cast<unsigned short*>(&h);
}

// ---------------------------------------------------------------------------
// K1: per-row t_enc (8ch MLP) + inp_f/inp_b = xc @ Wp + bp (K=10 skinny GEMM)
// one block per slab-local row, 256 threads. inp stored bf16.
// ---------------------------------------------------------------------------
__global__ __launch_bounds__(256) void k1_tenc_inp(
    const float* __restrict__ x, const float* __restrict__ t,
    const float* __restrict__ Wt1, const float* __restrict__ bt1,
    const float* __restrict__ Wt2, const float* __restrict__ bt2,
    const float* __restrict__ Wpf, const float* __restrict__ bpf,
    const float* __restrict__ Wpb, const float* __restrict__ bpb,
    float* __restrict__ t_enc,
    unsigned short* __restrict__ inp_f, unsigned short* __restrict__ inp_b)
{
    int row = blockIdx.x;
    int tid = threadIdx.x;
    __shared__ float s_r1[NT_], s_te[NT_], s_x[2];
    if (tid < NT_) {
        float tv = t[row];
        s_r1[tid] = fmaxf(tv * Wt1[tid] + bt1[tid], 0.f);
    }
    if (tid == 0) { s_x[0] = x[row*2+0]; s_x[1] = x[row*2+1]; }
    __syncthreads();
    if (tid < NT_) {
        float acc = bt2[tid];
        #pragma unroll
        for (int k = 0; k < NT_; k++) acc = fmaf(s_r1[k], Wt2[k*NT_+tid], acc);
        s_te[tid] = acc;
        t_enc[row*NT_+tid] = acc;
    }
    __syncthreads();
    float x0 = s_x[0], x1 = s_x[1];
    for (int c = tid; c < H_; c += 256) {
        float af = fmaf(x0, Wpf[c], fmaf(x1, Wpf[H_+c], bpf[c]));
        float ab = fmaf(x0, Wpb[c], fmaf(x1, Wpb[H_+c], bpb[c]));
        #pragma unroll
        for (int k = 0; k < NT_; k++) {
            af = fmaf(s_te[k], Wpf[(2+k)*H_+c], af);
            ab = fmaf(s_te[k], Wpb[(2+k)*H_+c], ab);
        }
        inp_f[(size_t)row*H_+c] = f2b(af);
        inp_b[(size_t)row*H_+c] = f2b(ab);
    }
}

// ---------------------------------------------------------------------------
// K3: gates GEMM (f32 compute). C-tile 64x64, two accumulators (z,h) per
// output. Epilogue: a = 1-sigmoid(z), b = sigmoid(z)*tanh(h), packed
// (bf16 a)|(bf16 b)<<16 into one uint32 per element.
// ---------------------------------------------------------------------------
__global__ __launch_bounds__(256) void k3_gates(
    const unsigned short* __restrict__ inp,
    const float* __restrict__ Wz, const float* __restrict__ bz,
    const float* __restrict__ Wh, const float* __restrict__ bh,
    unsigned int* __restrict__ ab_out)
{
    __shared__ float As[16][68];   // [k][m]
    __shared__ float Zs[16][68];   // [k][n]
    __shared__ float Hs[16][68];   // [k][n]
    int tid = threadIdx.x;
    int tx = tid & 15, ty = tid >> 4;
    int row0 = blockIdx.x * 64;
    int n0   = blockIdx.y * 64;

    int lr = tid >> 2;            // 0..63  A-tile row
    int lk = (tid & 3) * 4;       // k-chunk within 16
    int wk = tid >> 4;            // 0..15  W-tile k
    int wn = (tid & 15) * 4;      // W-tile col chunk

    float accz[4][4] = {{0}}, acch[4][4] = {{0}};

    for (int k0 = 0; k0 < H_; k0 += 16) {
        ushort4 av = *(const ushort4*)&inp[(size_t)(row0+lr)*H_ + k0 + lk];
        float4 zv = *(const float4*)&Wz[(size_t)(k0+wk)*H_ + n0 + wn];
        float4 hv = *(const float4*)&Wh[(size_t)(k0+wk)*H_ + n0 + wn];
        __syncthreads();
        As[lk+0][lr] = b2f(av.x); As[lk+1][lr] = b2f(av.y);
        As[lk+2][lr] = b2f(av.z); As[lk+3][lr] = b2f(av.w);
        *(float4*)&Zs[wk][wn] = zv;
        *(float4*)&Hs[wk][wn] = hv;
        __syncthreads();
        #pragma unroll
        for (int k = 0; k < 16; k++) {
            float4 a4 = *(const float4*)&As[k][ty*4];
            float4 z4 = *(const float4*)&Zs[k][tx*4];
            float4 h4 = *(const float4*)&Hs[k][tx*4];
            float am[4] = {a4.x, a4.y, a4.z, a4.w};
            float zn[4] = {z4.x, z4.y, z4.z, z4.w};
            float hn[4] = {h4.x, h4.y, h4.z, h4.w};
            #pragma unroll
            for (int m = 0; m < 4; m++)
                #pragma unroll
                for (int n = 0; n < 4; n++) {
                    accz[m][n] = fmaf(am[m], zn[n], accz[m][n]);
                    acch[m][n] = fmaf(am[m], hn[n], acch[m][n]);
                }
        }
    }

    #pragma unroll
    for (int m = 0; m < 4; m++) {
        int row = row0 + ty*4 + m;
        unsigned int pk[4];
        #pragma unroll
        for (int n = 0; n < 4; n++) {
            int col = n0 + tx*4 + n;
            float zarg = accz[m][n] + bz[col];
            float harg = acch[m][n] + bh[col];
            float zg = 1.f / (1.f + expf(-zarg));
            float a = 1.f - zg;
            float b = zg * tanhf(harg);
            pk[n] = (unsigned int)f2b(a) | ((unsigned int)f2b(b) << 16);
        }
        *(uint4*)&ab_out[(size_t)row*H_ + n0 + tx*4] =
            make_uint4(pk[0], pk[1], pk[2], pk[3]);
    }
}

// ---------------------------------------------------------------------------
// K4: linear scan, thread per (batch,channel). h stored bf16 (h_out may alias
// the dead inp buffer). reverse=0: h_out[l] = h before step l.
// reverse=1: h_out[l] = a[l+1]*h_out[l+1] + b[l+1], h_out[L-1] = 0.
// ---------------------------------------------------------------------------
__global__ __launch_bounds__(64) void k4_scan(
    const unsigned int* __restrict__ ab,
    unsigned short* __restrict__ h_out,
    int nb, int reverse)
{
    int gtid = blockIdx.x * 64 + threadIdx.x;
    if (gtid >= nb * H_) return;
    int col = gtid & (H_-1);
    int bb  = gtid >> 9;
    size_t base = (size_t)bb * L_ * H_ + col;
    float h = 0.f;
    if (!reverse) {
        for (int l0 = 0; l0 < L_; l0 += 8) {
            unsigned int v[8];
            #pragma unroll
            for (int j = 0; j < 8; j++) v[j] = ab[base + (size_t)(l0+j)*H_];
            #pragma unroll
            for (int j = 0; j < 8; j++) {
                size_t idx = base + (size_t)(l0+j)*H_;
                h_out[idx] = f2b(h);
                h = fmaf(b2f((unsigned short)(v[j] & 0xffffu)), h,
                         b2f((unsigned short)(v[j] >> 16)));
            }
        }
    } else {
        for (int l0 = L_-8; l0 >= 0; l0 -= 8) {
            unsigned int v[8];
            #pragma unroll
            for (int j = 7; j >= 0; j--) v[j] = ab[base + (size_t)(l0+j)*H_];
            #pragma unroll
            for (int j = 7; j >= 0; j--) {
                size_t idx = base + (size_t)(l0+j)*H_;
                h_out[idx] = f2b(h);
                h = fmaf(b2f((unsigned short)(v[j] & 0xffffu)), h,
                         b2f((unsigned short)(v[j] >> 16)));
            }
        }
    }
}

// ---------------------------------------------------------------------------
// K5: LayerNorm(1032) + time_scale + gelu(hbi@Wg1+bg1) @ Wg2 + bg2
// 8 rows/block; h_bi transposed [c][r] in LDS.
// ---------------------------------------------------------------------------
__global__ __launch_bounds__(256) void k5_head(
    const unsigned short* __restrict__ h_fwd, const unsigned short* __restrict__ h_bwd,
    const float* __restrict__ t_enc,
    const float* __restrict__ ln_g, const float* __restrict__ ln_b,
    const float* __restrict__ ts_p,
    const float* __restrict__ Wg1, const float* __restrict__ bg1,
    const float* __restrict__ Wg2, const float* __restrict__ bg2,
    float* __restrict__ out)
{
    const int RB = 8;
    __shared__ float hbiT[OUT_][RB];        // 33 KB
    __shared__ float redS[4][RB], redQ[4][RB];
    __shared__ float smu[RB], srs[RB];
    __shared__ float pr[RB][HEAD_];         // 8 KB
    int tid  = threadIdx.x;
    int row0 = blockIdx.x * RB;
    float ts = ts_p[0];

    for (int c = tid; c < OUT_; c += 256) {
        #pragma unroll
        for (int r = 0; r < RB; r++) {
            int row = row0 + r;
            float v;
            if (c < H_)        v = b2f(h_fwd[(size_t)row*H_ + c]);
            else if (c < 2*H_) v = b2f(h_bwd[(size_t)row*H_ + (c - H_)]);
            else               v = t_enc[row*NT_ + (c - 2*H_)];
            hbiT[c][r] = v;
        }
    }
    __syncthreads();

    float s[RB] = {0}, q[RB] = {0};
    for (int c = tid; c < OUT_; c += 256) {
        #pragma unroll
        for (int r = 0; r < RB; r++) { float v = hbiT[c][r]; s[r] += v; q[r] += v*v; }
    }
    #pragma unroll
    for (int off = 32; off > 0; off >>= 1) {
        #pragma unroll
        for (int r = 0; r < RB; r++) {
            s[r] += __shfl_down(s[r], off, 64);
            q[r] += __shfl_down(q[r], off, 64);
        }
    }
    int wid = tid >> 6;
    if ((tid & 63) == 0) {
        #pragma unroll
        for (int r = 0; r < RB; r++) { redS[wid][r] = s[r]; redQ[wid][r] = q[r]; }
    }
    __syncthreads();
    if (tid < RB) {
        float S = 0, Q = 0;
        #pragma unroll
        for (int w = 0; w < 4; w++) { S += redS[w][tid]; Q += redQ[w][tid]; }
        float mu  = S / (float)OUT_;
        float var = Q / (float)OUT_ - mu*mu;
        smu[tid] = mu;
        srs[tid] = rsqrtf(var + 1e-5f);
    }
    __syncthreads();

    for (int c = tid; c < OUT_; c += 256) {
        float g = ln_g[c], bta = ln_b[c];
        float scale = (c >= 2*H_) ? ts : 1.f;
        #pragma unroll
        for (int r = 0; r < RB; r++) {
            float v = (hbiT[c][r] - smu[r]) * srs[r];
            hbiT[c][r] = (v*g + bta) * scale;
        }
    }
    __syncthreads();

    int j = tid;
    float acc[RB];
    float bg = bg1[j];
    #pragma unroll
    for (int r = 0; r < RB; r++) acc[r] = bg;
    for (int c = 0; c < OUT_; c++) {
        float w = Wg1[(size_t)c*HEAD_ + j];
        float4 h0 = *(const float4*)&hbiT[c][0];
        float4 h1 = *(const float4*)&hbiT[c][4];
        acc[0] = fmaf(h0.x, w, acc[0]); acc[1] = fmaf(h0.y, w, acc[1]);
        acc[2] = fmaf(h0.z, w, acc[2]); acc[3] = fmaf(h0.w, w, acc[3]);
        acc[4] = fmaf(h1.x, w, acc[4]); acc[5] = fmaf(h1.y, w, acc[5]);
        acc[6] = fmaf(h1.z, w, acc[6]); acc[7] = fmaf(h1.w, w, acc[7]);
    }
    float w2 = Wg2[j];
    #pragma unroll
    for (int r = 0; r < RB; r++) {
        float g = acc[r];
        g = 0.5f * g * (1.f + erff(g * 0.70710678118654752f));
        pr[r][j] = g * w2;
    }
    __syncthreads();
    float s2 = 0.f;
    if (tid < 64) {
        int r = tid >> 3, i = tid & 7;
        for (int k2 = i; k2 < HEAD_; k2 += 8) s2 += pr[r][k2];
    }
    __syncthreads();
    if (tid < 64) pr[tid >> 3][tid & 7] = s2;
    __syncthreads();
    if (tid < RB) {
        float S = 0.f;
        #pragma unroll
        for (int k2 = 0; k2 < 8; k2++) S += pr[tid][k2];
        out[row0 + tid] = S + bg2[0];
    }
}

// ---------------------------------------------------------------------------
extern "C" void kernel_launch(void* const* d_in, const int* in_sizes, int n_in,
                              void* d_out, int out_size, void* d_ws, size_t ws_size,
                              hipStream_t stream)
{
    const float* x    = (const float*)d_in[0];
    const float* t    = (const float*)d_in[1];
    const float* Wt1  = (const float*)d_in[2];
    const float* bt1  = (const float*)d_in[3];
    const float* Wt2  = (const float*)d_in[4];
    const float* bt2  = (const float*)d_in[5];
    const float* Wpf  = (const float*)d_in[6];
    const float* bpf  = (const float*)d_in[7];
    const float* Wpb  = (const float*)d_in[8];
    const float* bpb  = (const float*)d_in[9];
    const float* Wzf  = (const float*)d_in[10];
    const float* bzf  = (const float*)d_in[11];
    const float* Whf  = (const float*)d_in[12];
    const float* bhf  = (const float*)d_in[13];
    const float* Wzb  = (const float*)d_in[14];
    const float* bzb  = (const float*)d_in[15];
    const float* Whb  = (const float*)d_in[16];
    const float* bhb  = (const float*)d_in[17];
    const float* ln_g = (const float*)d_in[18];
    const float* ln_b = (const float*)d_in[19];
    const float* tsc  = (const float*)d_in[20];
    const float* Wg1  = (const float*)d_in[21];
    const float* bg1  = (const float*)d_in[22];
    const float* Wg2  = (const float*)d_in[23];
    const float* bg2  = (const float*)d_in[24];
    float* out = (float*)d_out;

    // per-batch slab bytes: inpF(bf16) + inpB(bf16) + AB(u32) + tenc(f32)
    const size_t perBatch = (size_t)L_*H_*2 + (size_t)L_*H_*2
                          + (size_t)L_*H_*4 + (size_t)L_*NT_*4;
    int NB = B_;
    while (NB > 1 && (size_t)NB * perBatch > ws_size) NB >>= 1;

    char* p = (char*)d_ws;
    unsigned short* inpF = (unsigned short*)p; p += (size_t)NB*L_*H_*2;
    unsigned short* inpB = (unsigned short*)p; p += (size_t)NB*L_*H_*2;
    unsigned int*   AB   = (unsigned int*)p;   p += (size_t)NB*L_*H_*4;
    float*          tenc = (float*)p;

    for (int b0 = 0; b0 < B_; b0 += NB) {
        int rows = NB * L_;
        k1_tenc_inp<<<rows, 256, 0, stream>>>(
            x + (size_t)b0*L_*2, t + (size_t)b0*L_,
            Wt1, bt1, Wt2, bt2, Wpf, bpf, Wpb, bpb,
            tenc, inpF, inpB);

        dim3 g3(rows/64, H_/64);
        k3_gates<<<g3, 256, 0, stream>>>(inpF, Wzf, bzf, Whf, bhf, AB);
        k4_scan<<<(NB*H_+63)/64, 64, 0, stream>>>(AB, inpF /* -> h_fwd */, NB, 0);

        k3_gates<<<g3, 256, 0, stream>>>(inpB, Wzb, bzb, Whb, bhb, AB);
        k4_scan<<<(NB*H_+63)/64, 64, 0, stream>>>(AB, inpB /* -> h_bwd */, NB, 1);

        k5_head<<<rows/8, 256, 0, stream>>>(
            inpF, inpB, tenc, ln_g, ln_b, tsc,
            Wg1, bg1, Wg2, bg2, out + (size_t)b0*L_);
    }
}

// Round 3
// 442.080 us; speedup vs baseline: 3.1634x; 3.1634x over previous
//
#include <hip/hip_runtime.h>
#include <hip/hip_bf16.h>
#include <math.h>

#define B_    16
#define L_    2048
#define H_    512
#define NT_   8
#define OUT_  1032
#define KPAD_ 1056
#define HEAD_ 256
#define CH_   16
#define CL_   (L_/CH_)   // 128

typedef short bf16x8 __attribute__((ext_vector_type(8)));
typedef float f32x4  __attribute__((ext_vector_type(4)));

__device__ __forceinline__ float b2f(unsigned short u) {
    union { unsigned int u32; float f; } v; v.u32 = ((unsigned int)u) << 16; return v.f;
}
__device__ __forceinline__ unsigned short f2b(float f) {
    __hip_bfloat16 h = __float2bfloat16(f);
    return *reinterpret_cast<unsigned short*>(&h);
}

// ---------------------------------------------------------------------------
// kT: transpose + f32->bf16. in f32 [R][C] -> out bf16 [C][RP], zero r>=R.
// ---------------------------------------------------------------------------
__global__ __launch_bounds__(256) void kT(const float* __restrict__ in,
                                          unsigned short* __restrict__ out,
                                          int R, int C, int RP)
{
    __shared__ float tile[32][33];
    int c0 = blockIdx.x * 32, r0 = blockIdx.y * 32;
    int tx = threadIdx.x & 31, ty = threadIdx.x >> 5;  // 32 x 8
    #pragma unroll
    for (int j = 0; j < 32; j += 8) {
        int r = r0 + ty + j, c = c0 + tx;
        tile[ty + j][tx] = (r < R && c < C) ? in[(size_t)r*C + c] : 0.f;
    }
    __syncthreads();
    #pragma unroll
    for (int j = 0; j < 32; j += 8) {
        int c = c0 + ty + j, r = r0 + tx;
        if (c < C && r < RP) out[(size_t)c*RP + r] = f2b(tile[tx][ty + j]);
    }
}

// ---------------------------------------------------------------------------
// K1: t_enc MLP + inp = xc @ Wp + bp (K=10), bf16 out. one block per row.
// ---------------------------------------------------------------------------
__global__ __launch_bounds__(256) void k1_tenc_inp(
    const float* __restrict__ x, const float* __restrict__ t,
    const float* __restrict__ Wt1, const float* __restrict__ bt1,
    const float* __restrict__ Wt2, const float* __restrict__ bt2,
    const float* __restrict__ Wpf, const float* __restrict__ bpf,
    const float* __restrict__ Wpb, const float* __restrict__ bpb,
    float* __restrict__ t_enc,
    unsigned short* __restrict__ inp_f, unsigned short* __restrict__ inp_b)
{
    int row = blockIdx.x;
    int tid = threadIdx.x;
    __shared__ float s_r1[NT_], s_te[NT_], s_x[2];
    if (tid < NT_) {
        float tv = t[row];
        s_r1[tid] = fmaxf(tv * Wt1[tid] + bt1[tid], 0.f);
    }
    if (tid == 0) { s_x[0] = x[row*2+0]; s_x[1] = x[row*2+1]; }
    __syncthreads();
    if (tid < NT_) {
        float acc = bt2[tid];
        #pragma unroll
        for (int k = 0; k < NT_; k++) acc = fmaf(s_r1[k], Wt2[k*NT_+tid], acc);
        s_te[tid] = acc;
        t_enc[row*NT_+tid] = acc;
    }
    __syncthreads();
    float x0 = s_x[0], x1 = s_x[1];
    for (int c = tid; c < H_; c += 256) {
        float af = fmaf(x0, Wpf[c], fmaf(x1, Wpf[H_+c], bpf[c]));
        float ab = fmaf(x0, Wpb[c], fmaf(x1, Wpb[H_+c], bpb[c]));
        #pragma unroll
        for (int k = 0; k < NT_; k++) {
            af = fmaf(s_te[k], Wpf[(2+k)*H_+c], af);
            ab = fmaf(s_te[k], Wpb[(2+k)*H_+c], ab);
        }
        inp_f[(size_t)row*H_+c] = f2b(af);
        inp_b[(size_t)row*H_+c] = f2b(ab);
    }
}

// ---------------------------------------------------------------------------
// K3 (MFMA): ab = pack(1-sig(inp@Wz+bz), sig*tanh(inp@Wh+bh)).
// Tile 128x64, BK=32, 4 waves (2x2), wave tile 64x32 = 4x2 frags of 16x16x32.
// A LDS rows padded to 40 shorts (80B) -> 2-way-max bank aliasing (free).
// ---------------------------------------------------------------------------
__global__ __launch_bounds__(256) void k3_mfma(
    const unsigned short* __restrict__ inp,   // [M][512] bf16
    const unsigned short* __restrict__ WzT,   // [512][512] bf16, [n][k]
    const unsigned short* __restrict__ WhT,
    const float* __restrict__ bz, const float* __restrict__ bh,
    unsigned int* __restrict__ ab_out)
{
    __shared__ __align__(16) unsigned short As[128*40];
    __shared__ __align__(16) unsigned short Zs[64*40];
    __shared__ __align__(16) unsigned short Hs[64*40];
    int tid = threadIdx.x;
    int lane = tid & 63, w = tid >> 6;
    int wm = w >> 1, wn = w & 1;
    int row0 = blockIdx.x * 128;
    int n0   = blockIdx.y * 64;

    f32x4 accz[4][2], acch[4][2];
    #pragma unroll
    for (int m = 0; m < 4; m++)
        #pragma unroll
        for (int n = 0; n < 2; n++) {
            accz[m][n] = (f32x4){0.f,0.f,0.f,0.f};
            acch[m][n] = (f32x4){0.f,0.f,0.f,0.f};
        }

    int ar = tid >> 1, aseg = tid & 1;           // A stage: 32B/thread
    int bu = tid & 127;
    int br = bu >> 1, bseg = bu & 1;             // B stage: 32B/thread
    const unsigned short* WT = (tid < 128) ? WzT : WhT;
    unsigned short* BS = (tid < 128) ? Zs : Hs;

    int kg = lane >> 4, lr = lane & 15;

    for (int k0 = 0; k0 < H_; k0 += 32) {
        const uint4* ga = (const uint4*)&inp[(size_t)(row0+ar)*H_ + k0 + aseg*16];
        uint4 va0 = ga[0], va1 = ga[1];
        const uint4* gb = (const uint4*)&WT[(size_t)(n0+br)*H_ + k0 + bseg*16];
        uint4 vb0 = gb[0], vb1 = gb[1];
        __syncthreads();
        *(uint4*)&As[ar*40 + aseg*16]     = va0;
        *(uint4*)&As[ar*40 + aseg*16 + 8] = va1;
        *(uint4*)&BS[br*40 + bseg*16]     = vb0;
        *(uint4*)&BS[br*40 + bseg*16 + 8] = vb1;
        __syncthreads();
        bf16x8 af[4], zf[2], hf[2];
        #pragma unroll
        for (int m = 0; m < 4; m++)
            af[m] = *(const bf16x8*)&As[(wm*64 + m*16 + lr)*40 + kg*8];
        #pragma unroll
        for (int n = 0; n < 2; n++) {
            zf[n] = *(const bf16x8*)&Zs[(wn*32 + n*16 + lr)*40 + kg*8];
            hf[n] = *(const bf16x8*)&Hs[(wn*32 + n*16 + lr)*40 + kg*8];
        }
        #pragma unroll
        for (int m = 0; m < 4; m++)
            #pragma unroll
            for (int n = 0; n < 2; n++) {
                accz[m][n] = __builtin_amdgcn_mfma_f32_16x16x32_bf16(af[m], zf[n], accz[m][n], 0, 0, 0);
                acch[m][n] = __builtin_amdgcn_mfma_f32_16x16x32_bf16(af[m], hf[n], acch[m][n], 0, 0, 0);
            }
    }

    #pragma unroll
    for (int m = 0; m < 4; m++)
        #pragma unroll
        for (int n = 0; n < 2; n++) {
            int colg = n0 + wn*32 + n*16 + lr;
            float bzv = bz[colg], bhv = bh[colg];
            #pragma unroll
            for (int r = 0; r < 4; r++) {
                int rowg = row0 + wm*64 + m*16 + kg*4 + r;
                float zarg = accz[m][n][r] + bzv;
                float harg = acch[m][n][r] + bhv;
                float zg = 1.f / (1.f + expf(-zarg));
                float a = 1.f - zg;
                float b = zg * tanhf(harg);
                ab_out[(size_t)rowg*H_ + colg] =
                    (unsigned int)f2b(a) | ((unsigned int)f2b(b) << 16);
            }
        }
}

// ---------------------------------------------------------------------------
// K4a: chunked scan pass A. In-place: read gate pack(a,b), write pack(S,PP).
// Per-thread chunk of 128 steps; f32 carries (Scar,Pcar) per chunk.
// ---------------------------------------------------------------------------
__global__ __launch_bounds__(256) void k4a(
    unsigned int* __restrict__ ABF, unsigned int* __restrict__ ABB,
    float* __restrict__ Scar, float* __restrict__ Pcar, int nb)
{
    int g = blockIdx.x*256 + threadIdx.x;
    int col   = g & (H_-1);
    int chunk = (g >> 9) & (CH_-1);
    int rest  = g >> 13;
    int bb    = rest % nb;
    int dir   = rest / nb;
    unsigned int* AB = dir ? ABB : ABF;
    size_t base = (size_t)bb * L_ * H_ + col;
    float h = 0.f, pp = 1.f;
    if (dir == 0) {
        int lo = chunk * CL_;
        for (int p = 0; p < CL_; p += 8) {
            unsigned int v[8];
            #pragma unroll
            for (int j = 0; j < 8; j++) v[j] = AB[base + (size_t)(lo+p+j)*H_];
            #pragma unroll
            for (int j = 0; j < 8; j++) {
                size_t idx = base + (size_t)(lo+p+j)*H_;
                float av = b2f((unsigned short)(v[j] & 0xffffu));
                float bv = b2f((unsigned short)(v[j] >> 16));
                AB[idx] = (unsigned int)f2b(h) | ((unsigned int)f2b(pp) << 16);
                h = fmaf(av, h, bv);
                pp *= av;
            }
        }
    } else {
        int hi = chunk * CL_ + CL_ - 1;
        for (int p = 0; p < CL_; p += 8) {
            unsigned int v[8];
            #pragma unroll
            for (int j = 0; j < 8; j++) v[j] = AB[base + (size_t)(hi-p-j)*H_];
            #pragma unroll
            for (int j = 0; j < 8; j++) {
                size_t idx = base + (size_t)(hi-p-j)*H_;
                float av = b2f((unsigned short)(v[j] & 0xffffu));
                float bv = b2f((unsigned short)(v[j] >> 16));
                AB[idx] = (unsigned int)f2b(h) | ((unsigned int)f2b(pp) << 16);
                h = fmaf(av, h, bv);
                pp *= av;
            }
        }
    }
    int ci = ((dir*nb + bb)*CH_ + chunk)*H_ + col;
    Scar[ci] = h; Pcar[ci] = pp;
}

// K4b: chain carries across chunks (fwd: left->right, bwd: right->left).
__global__ __launch_bounds__(256) void k4b(
    const float* __restrict__ Scar, const float* __restrict__ Pcar,
    float* __restrict__ Hstart, int nb)
{
    int g = blockIdx.x*256 + threadIdx.x;
    int col  = g & (H_-1);
    int rest = g >> 9;
    int bb   = rest % nb;
    int dir  = rest / nb;
    int baseci = (dir*nb + bb)*CH_;
    float h = 0.f;
    if (dir == 0) {
        for (int c = 0; c < CH_; c++) {
            int ci = (baseci + c)*H_ + col;
            Hstart[ci] = h;
            h = Scar[ci] + Pcar[ci]*h;
        }
    } else {
        for (int c = CH_-1; c >= 0; c--) {
            int ci = (baseci + c)*H_ + col;
            Hstart[ci] = h;
            h = Scar[ci] + Pcar[ci]*h;
        }
    }
}

// K4c: h_out = S + PP*Hstart (elementwise), bf16 out.
__global__ __launch_bounds__(256) void k4c(
    const unsigned int* __restrict__ SPF, const unsigned int* __restrict__ SPB,
    const float* __restrict__ Hstart,
    unsigned short* __restrict__ hF, unsigned short* __restrict__ hB, int nb)
{
    int g = blockIdx.x*256 + threadIdx.x;
    int col   = g & (H_-1);
    int chunk = (g >> 9) & (CH_-1);
    int rest  = g >> 13;
    int bb    = rest % nb;
    int dir   = rest / nb;
    const unsigned int* SP = dir ? SPB : SPF;
    unsigned short* hout = dir ? hB : hF;
    size_t base = (size_t)bb * L_ * H_ + col;
    float h0 = Hstart[((dir*nb + bb)*CH_ + chunk)*H_ + col];
    int lo = chunk * CL_;
    for (int p = 0; p < CL_; p += 8) {
        unsigned int v[8];
        #pragma unroll
        for (int j = 0; j < 8; j++) v[j] = SP[base + (size_t)(lo+p+j)*H_];
        #pragma unroll
        for (int j = 0; j < 8; j++) {
            float S  = b2f((unsigned short)(v[j] & 0xffffu));
            float PP = b2f((unsigned short)(v[j] >> 16));
            hout[base + (size_t)(lo+p+j)*H_] = f2b(fmaf(PP, h0, S));
        }
    }
}

// ---------------------------------------------------------------------------
// K5a: LayerNorm(1032) + affine + time_scale -> hbi bf16 [M][1056] (padded 0).
// one wave per row, 4 rows per block.
// ---------------------------------------------------------------------------
__global__ __launch_bounds__(256) void k5a_ln(
    const unsigned short* __restrict__ hf, const unsigned short* __restrict__ hb,
    const float* __restrict__ tenc,
    const float* __restrict__ ln_g, const float* __restrict__ ln_b,
    const float* __restrict__ tsp,
    unsigned short* __restrict__ hbi)
{
    int wv = threadIdx.x >> 6, lane = threadIdx.x & 63;
    size_t row = (size_t)blockIdx.x*4 + wv;
    float ts = tsp[0];
    uint4 uf = *(const uint4*)&hf[row*H_ + lane*8];
    uint4 ub = *(const uint4*)&hb[row*H_ + lane*8];
    const unsigned short* pf = (const unsigned short*)&uf;
    const unsigned short* pb = (const unsigned short*)&ub;
    float fv[8], bv[8];
    float S = 0.f, Q = 0.f;
    #pragma unroll
    for (int j = 0; j < 8; j++) {
        fv[j] = b2f(pf[j]); S += fv[j]; Q += fv[j]*fv[j];
        bv[j] = b2f(pb[j]); S += bv[j]; Q += bv[j]*bv[j];
    }
    float tv = 0.f;
    if (lane < NT_) { tv = tenc[row*NT_ + lane]; S += tv; Q += tv*tv; }
    #pragma unroll
    for (int off = 32; off > 0; off >>= 1) {
        S += __shfl_xor(S, off, 64);
        Q += __shfl_xor(Q, off, 64);
    }
    float mu = S * (1.f/1032.f);
    float rs = rsqrtf(Q * (1.f/1032.f) - mu*mu + 1e-5f);
    unsigned short o[8];
    int c0 = lane*8;
    #pragma unroll
    for (int j = 0; j < 8; j++)
        o[j] = f2b((fv[j]-mu)*rs*ln_g[c0+j] + ln_b[c0+j]);
    *(uint4*)&hbi[row*KPAD_ + c0] = *(const uint4*)o;
    #pragma unroll
    for (int j = 0; j < 8; j++)
        o[j] = f2b((bv[j]-mu)*rs*ln_g[H_+c0+j] + ln_b[H_+c0+j]);
    *(uint4*)&hbi[row*KPAD_ + H_ + c0] = *(const uint4*)o;
    if (lane < NT_) {
        int c = 2*H_ + lane;
        hbi[row*KPAD_ + c] = f2b(((tv-mu)*rs*ln_g[c] + ln_b[c]) * ts);
    } else if (lane < 32) {
        hbi[row*KPAD_ + OUT_ + (lane-8)] = 0;
    }
}

// ---------------------------------------------------------------------------
// K5b (MFMA): out = gelu(hbi@Wg1+bg1) @ Wg2 + bg2.
// Tile 64 rows x 256 cols, BK=32, K=1056. Waves 2x2; wave tile 32x128 = 2x8.
// In-register gelu*Wg2 + shfl row-reduce (no atomics).
// ---------------------------------------------------------------------------
__global__ __launch_bounds__(256) void k5b_head(
    const unsigned short* __restrict__ hbi,   // [M][1056]
    const unsigned short* __restrict__ Wg1T,  // [256][1056]
    const float* __restrict__ bg1, const float* __restrict__ Wg2,
    const float* __restrict__ bg2,
    float* __restrict__ out)
{
    __shared__ __align__(16) unsigned short As[64*40];
    __shared__ __align__(16) unsigned short Bs[256*40];
    __shared__ float red[2][64];
    int tid = threadIdx.x, lane = tid & 63, w = tid >> 6;
    int wm = w >> 1, wn = w & 1;
    int row0 = blockIdx.x * 64;
    int kg = lane >> 4, lr = lane & 15;

    f32x4 acc[2][8];
    #pragma unroll
    for (int m = 0; m < 2; m++)
        #pragma unroll
        for (int n = 0; n < 8; n++) acc[m][n] = (f32x4){0.f,0.f,0.f,0.f};

    int ar = tid >> 2, aseg = tid & 3;

    for (int k0 = 0; k0 < KPAD_; k0 += 32) {
        uint4 va = *(const uint4*)&hbi[(size_t)(row0+ar)*KPAD_ + k0 + aseg*8];
        uint4 vb[4];
        #pragma unroll
        for (int j = 0; j < 4; j++)
            vb[j] = *(const uint4*)&Wg1T[(size_t)tid*KPAD_ + k0 + j*8];
        __syncthreads();
        *(uint4*)&As[ar*40 + aseg*8] = va;
        #pragma unroll
        for (int j = 0; j < 4; j++)
            *(uint4*)&Bs[tid*40 + j*8] = vb[j];
        __syncthreads();
        bf16x8 af[2], bf[8];
        #pragma unroll
        for (int m = 0; m < 2; m++)
            af[m] = *(const bf16x8*)&As[(wm*32 + m*16 + lr)*40 + kg*8];
        #pragma unroll
        for (int n = 0; n < 8; n++)
            bf[n] = *(const bf16x8*)&Bs[(wn*128 + n*16 + lr)*40 + kg*8];
        #pragma unroll
        for (int m = 0; m < 2; m++)
            #pragma unroll
            for (int n = 0; n < 8; n++)
                acc[m][n] = __builtin_amdgcn_mfma_f32_16x16x32_bf16(af[m], bf[n], acc[m][n], 0, 0, 0);
    }

    float rsum[2][4] = {{0.f,0.f,0.f,0.f},{0.f,0.f,0.f,0.f}};
    #pragma unroll
    for (int n = 0; n < 8; n++) {
        int colg = wn*128 + n*16 + lr;
        float bgv = bg1[colg], w2v = Wg2[colg];
        #pragma unroll
        for (int m = 0; m < 2; m++)
            #pragma unroll
            for (int r = 0; r < 4; r++) {
                float gv = acc[m][n][r] + bgv;
                gv = 0.5f*gv*(1.f + erff(gv*0.70710678118654752f));
                rsum[m][r] = fmaf(gv, w2v, rsum[m][r]);
            }
    }
    #pragma unroll
    for (int off = 1; off < 16; off <<= 1)
        #pragma unroll
        for (int m = 0; m < 2; m++)
            #pragma unroll
            for (int r = 0; r < 4; r++)
                rsum[m][r] += __shfl_xor(rsum[m][r], off, 64);
    if (lr == 0) {
        #pragma unroll
        for (int m = 0; m < 2; m++)
            #pragma unroll
            for (int r = 0; r < 4; r++)
                red[wn][wm*32 + m*16 + kg*4 + r] = rsum[m][r];
    }
    __syncthreads();
    if (tid < 64) out[row0 + tid] = red[0][tid] + red[1][tid] + bg2[0];
}

// ---------------------------------------------------------------------------
extern "C" void kernel_launch(void* const* d_in, const int* in_sizes, int n_in,
                              void* d_out, int out_size, void* d_ws, size_t ws_size,
                              hipStream_t stream)
{
    const float* x    = (const float*)d_in[0];
    const float* t    = (const float*)d_in[1];
    const float* Wt1  = (const float*)d_in[2];
    const float* bt1  = (const float*)d_in[3];
    const float* Wt2  = (const float*)d_in[4];
    const float* bt2  = (const float*)d_in[5];
    const float* Wpf  = (const float*)d_in[6];
    const float* bpf  = (const float*)d_in[7];
    const float* Wpb  = (const float*)d_in[8];
    const float* bpb  = (const float*)d_in[9];
    const float* Wzf  = (const float*)d_in[10];
    const float* bzf  = (const float*)d_in[11];
    const float* Whf  = (const float*)d_in[12];
    const float* bhf  = (const float*)d_in[13];
    const float* Wzb  = (const float*)d_in[14];
    const float* bzb  = (const float*)d_in[15];
    const float* Whb  = (const float*)d_in[16];
    const float* bhb  = (const float*)d_in[17];
    const float* ln_g = (const float*)d_in[18];
    const float* ln_b = (const float*)d_in[19];
    const float* tsc  = (const float*)d_in[20];
    const float* Wg1  = (const float*)d_in[21];
    const float* bg1  = (const float*)d_in[22];
    const float* Wg2  = (const float*)d_in[23];
    const float* bg2  = (const float*)d_in[24];
    float* out = (float*)d_out;

    char* p = (char*)d_ws;
    auto carve = [&](size_t bytes) -> char* {
        char* q = p; p += (bytes + 255) & ~(size_t)255; return q;
    };

    // fixed: transposed bf16 weights
    unsigned short* WzTf = (unsigned short*)carve((size_t)H_*H_*2);
    unsigned short* WhTf = (unsigned short*)carve((size_t)H_*H_*2);
    unsigned short* WzTb = (unsigned short*)carve((size_t)H_*H_*2);
    unsigned short* WhTb = (unsigned short*)carve((size_t)H_*H_*2);
    unsigned short* Wg1T = (unsigned short*)carve((size_t)HEAD_*KPAD_*2);

    const size_t perBatch = (size_t)L_*H_*2*2      // inpF+inpB
                          + (size_t)L_*H_*4*2      // ABF+ABB
                          + (size_t)L_*NT_*4       // tenc
                          + (size_t)CH_*H_*4*3*2;  // carries (both dirs)
    size_t fixedUsed = (size_t)(p - (char*)d_ws) + 64*1024;
    int NB = B_;
    while (NB > 1 && fixedUsed + (size_t)NB*perBatch > ws_size) NB >>= 1;

    unsigned short* inpF = (unsigned short*)carve((size_t)NB*L_*H_*2);
    unsigned short* inpB = (unsigned short*)carve((size_t)NB*L_*H_*2);
    unsigned int*   ABF  = (unsigned int*)carve((size_t)NB*L_*H_*4);
    unsigned int*   ABB  = (unsigned int*)carve((size_t)NB*L_*H_*4);
    float* tenc   = (float*)carve((size_t)NB*L_*NT_*4);
    float* Scar   = (float*)carve((size_t)2*NB*CH_*H_*4);
    float* Pcar   = (float*)carve((size_t)2*NB*CH_*H_*4);
    float* Hstart = (float*)carve((size_t)2*NB*CH_*H_*4);
    unsigned short* hbi = (unsigned short*)ABF;   // alias: ABF dead after k4c
    // (KPAD_*2 = 2112 <= H_*4 = 2048? NO: 2112 > 2048 -> spills into ABB
    //  by NB*L_*64 bytes; ABB is also dead after k4c, and ABF+ABB are
    //  contiguous carve-outs, so hbi fits inside ABF∪ABB.)

    // prep: weight transposes
    {
        dim3 g(H_/32, H_/32);
        kT<<<g, 256, 0, stream>>>(Wzf, WzTf, H_, H_, H_);
        kT<<<g, 256, 0, stream>>>(Whf, WhTf, H_, H_, H_);
        kT<<<g, 256, 0, stream>>>(Wzb, WzTb, H_, H_, H_);
        kT<<<g, 256, 0, stream>>>(Whb, WhTb, H_, H_, H_);
        dim3 gg(HEAD_/32, KPAD_/32);
        kT<<<gg, 256, 0, stream>>>(Wg1, Wg1T, OUT_, HEAD_, KPAD_);
    }

    for (int b0 = 0; b0 < B_; b0 += NB) {
        int rows = NB * L_;
        k1_tenc_inp<<<rows, 256, 0, stream>>>(
            x + (size_t)b0*L_*2, t + (size_t)b0*L_,
            Wt1, bt1, Wt2, bt2, Wpf, bpf, Wpb, bpb,
            tenc, inpF, inpB);

        dim3 g3(rows/128, H_/64);
        k3_mfma<<<g3, 256, 0, stream>>>(inpF, WzTf, WhTf, bzf, bhf, ABF);
        k3_mfma<<<g3, 256, 0, stream>>>(inpB, WzTb, WhTb, bzb, bhb, ABB);

        int scanThreads = 2*NB*H_*CH_;
        k4a<<<scanThreads/256, 256, 0, stream>>>(ABF, ABB, Scar, Pcar, NB);
        k4b<<<(2*NB*H_)/256, 256, 0, stream>>>(Scar, Pcar, Hstart, NB);
        k4c<<<scanThreads/256, 256, 0, stream>>>(ABF, ABB, Hstart, inpF, inpB, NB);

        k5a_ln<<<rows/4, 256, 0, stream>>>(inpF, inpB, tenc, ln_g, ln_b, tsc, hbi);
        k5b_head<<<rows/64, 256, 0, stream>>>(hbi, Wg1T, bg1, Wg2, bg2,
                                              out + (size_t)b0*L_);
    }
}

// Round 4
// 355.040 us; speedup vs baseline: 3.9389x; 1.2452x over previous
//
#include <hip/hip_runtime.h>
#include <hip/hip_bf16.h>
#include <math.h>

#define B_    16
#define L_    2048
#define H_    512
#define NT_   8
#define OUT_  1032
#define KPAD_ 1056
#define KSTR_ 1064
#define HEAD_ 256
#define CH_   16
#define CL_   (L_/CH_)   // 128

typedef short bf16x8 __attribute__((ext_vector_type(8)));
typedef float f32x4  __attribute__((ext_vector_type(4)));

__device__ __forceinline__ float b2f(unsigned short u) {
    union { unsigned int u32; float f; } v; v.u32 = ((unsigned int)u) << 16; return v.f;
}
__device__ __forceinline__ unsigned short f2b(float f) {
    __hip_bfloat16 h = __float2bfloat16(f);
    return *reinterpret_cast<unsigned short*>(&h);
}

// ---------------------------------------------------------------------------
// kT: transpose + f32->bf16. in f32 [R][C] -> out bf16 [C][RP], zero r>=R.
// ---------------------------------------------------------------------------
__global__ __launch_bounds__(256) void kT(const float* __restrict__ in,
                                          unsigned short* __restrict__ out,
                                          int R, int C, int RP)
{
    __shared__ float tile[32][33];
    int c0 = blockIdx.x * 32, r0 = blockIdx.y * 32;
    int tx = threadIdx.x & 31, ty = threadIdx.x >> 5;  // 32 x 8
    #pragma unroll
    for (int j = 0; j < 32; j += 8) {
        int r = r0 + ty + j, c = c0 + tx;
        tile[ty + j][tx] = (r < R && c < C) ? in[(size_t)r*C + c] : 0.f;
    }
    __syncthreads();
    #pragma unroll
    for (int j = 0; j < 32; j += 8) {
        int c = c0 + ty + j, r = r0 + tx;
        if (c < C && r < RP) out[(size_t)c*RP + r] = f2b(tile[tx][ty + j]);
    }
}

// ---------------------------------------------------------------------------
// K1: t_enc MLP + inp = xc @ Wp + bp (K=10), bf16 out. one block per row.
// ---------------------------------------------------------------------------
__global__ __launch_bounds__(256) void k1_tenc_inp(
    const float* __restrict__ x, const float* __restrict__ t,
    const float* __restrict__ Wt1, const float* __restrict__ bt1,
    const float* __restrict__ Wt2, const float* __restrict__ bt2,
    const float* __restrict__ Wpf, const float* __restrict__ bpf,
    const float* __restrict__ Wpb, const float* __restrict__ bpb,
    float* __restrict__ t_enc,
    unsigned short* __restrict__ inp_f, unsigned short* __restrict__ inp_b)
{
    int row = blockIdx.x;
    int tid = threadIdx.x;
    __shared__ float s_r1[NT_], s_te[NT_], s_x[2];
    if (tid < NT_) {
        float tv = t[row];
        s_r1[tid] = fmaxf(tv * Wt1[tid] + bt1[tid], 0.f);
    }
    if (tid == 0) { s_x[0] = x[row*2+0]; s_x[1] = x[row*2+1]; }
    __syncthreads();
    if (tid < NT_) {
        float acc = bt2[tid];
        #pragma unroll
        for (int k = 0; k < NT_; k++) acc = fmaf(s_r1[k], Wt2[k*NT_+tid], acc);
        s_te[tid] = acc;
        t_enc[row*NT_+tid] = acc;
    }
    __syncthreads();
    float x0 = s_x[0], x1 = s_x[1];
    for (int c = tid; c < H_; c += 256) {
        float af = fmaf(x0, Wpf[c], fmaf(x1, Wpf[H_+c], bpf[c]));
        float ab = fmaf(x0, Wpb[c], fmaf(x1, Wpb[H_+c], bpb[c]));
        #pragma unroll
        for (int k = 0; k < NT_; k++) {
            af = fmaf(s_te[k], Wpf[(2+k)*H_+c], af);
            ab = fmaf(s_te[k], Wpb[(2+k)*H_+c], ab);
        }
        inp_f[(size_t)row*H_+c] = f2b(af);
        inp_b[(size_t)row*H_+c] = f2b(ab);
    }
}

// ---------------------------------------------------------------------------
// K3 (MFMA): ab = pack(1-sig(inp@Wz+bz), sig*tanh(inp@Wh+bh)).
// Tile 128x64, BK=32, 4 waves (2x2), wave tile 64x32 = 4x2 frags of 16x16x32.
// ---------------------------------------------------------------------------
__global__ __launch_bounds__(256) void k3_mfma(
    const unsigned short* __restrict__ inp,   // [M][512] bf16
    const unsigned short* __restrict__ WzT,   // [512][512] bf16, [n][k]
    const unsigned short* __restrict__ WhT,
    const float* __restrict__ bz, const float* __restrict__ bh,
    unsigned int* __restrict__ ab_out)
{
    __shared__ __align__(16) unsigned short As[128*40];
    __shared__ __align__(16) unsigned short Zs[64*40];
    __shared__ __align__(16) unsigned short Hs[64*40];
    int tid = threadIdx.x;
    int lane = tid & 63, w = tid >> 6;
    int wm = w >> 1, wn = w & 1;
    int row0 = blockIdx.x * 128;
    int n0   = blockIdx.y * 64;

    f32x4 accz[4][2], acch[4][2];
    #pragma unroll
    for (int m = 0; m < 4; m++)
        #pragma unroll
        for (int n = 0; n < 2; n++) {
            accz[m][n] = (f32x4){0.f,0.f,0.f,0.f};
            acch[m][n] = (f32x4){0.f,0.f,0.f,0.f};
        }

    int ar = tid >> 1, aseg = tid & 1;
    int bu = tid & 127;
    int br = bu >> 1, bseg = bu & 1;
    const unsigned short* WT = (tid < 128) ? WzT : WhT;
    unsigned short* BS = (tid < 128) ? Zs : Hs;

    int kg = lane >> 4, lr = lane & 15;

    for (int k0 = 0; k0 < H_; k0 += 32) {
        const uint4* ga = (const uint4*)&inp[(size_t)(row0+ar)*H_ + k0 + aseg*16];
        uint4 va0 = ga[0], va1 = ga[1];
        const uint4* gb = (const uint4*)&WT[(size_t)(n0+br)*H_ + k0 + bseg*16];
        uint4 vb0 = gb[0], vb1 = gb[1];
        __syncthreads();
        *(uint4*)&As[ar*40 + aseg*16]     = va0;
        *(uint4*)&As[ar*40 + aseg*16 + 8] = va1;
        *(uint4*)&BS[br*40 + bseg*16]     = vb0;
        *(uint4*)&BS[br*40 + bseg*16 + 8] = vb1;
        __syncthreads();
        bf16x8 af[4], zf[2], hf[2];
        #pragma unroll
        for (int m = 0; m < 4; m++)
            af[m] = *(const bf16x8*)&As[(wm*64 + m*16 + lr)*40 + kg*8];
        #pragma unroll
        for (int n = 0; n < 2; n++) {
            zf[n] = *(const bf16x8*)&Zs[(wn*32 + n*16 + lr)*40 + kg*8];
            hf[n] = *(const bf16x8*)&Hs[(wn*32 + n*16 + lr)*40 + kg*8];
        }
        #pragma unroll
        for (int m = 0; m < 4; m++)
            #pragma unroll
            for (int n = 0; n < 2; n++) {
                accz[m][n] = __builtin_amdgcn_mfma_f32_16x16x32_bf16(af[m], zf[n], accz[m][n], 0, 0, 0);
                acch[m][n] = __builtin_amdgcn_mfma_f32_16x16x32_bf16(af[m], hf[n], acch[m][n], 0, 0, 0);
            }
    }

    #pragma unroll
    for (int m = 0; m < 4; m++)
        #pragma unroll
        for (int n = 0; n < 2; n++) {
            int colg = n0 + wn*32 + n*16 + lr;
            float bzv = bz[colg], bhv = bh[colg];
            #pragma unroll
            for (int r = 0; r < 4; r++) {
                int rowg = row0 + wm*64 + m*16 + kg*4 + r;
                float zarg = accz[m][n][r] + bzv;
                float harg = acch[m][n][r] + bhv;
                float zg = 1.f / (1.f + expf(-zarg));
                float a = 1.f - zg;
                float b = zg * tanhf(harg);
                ab_out[(size_t)rowg*H_ + colg] =
                    (unsigned int)f2b(a) | ((unsigned int)f2b(b) << 16);
            }
        }
}

// ---------------------------------------------------------------------------
// K4a: chunked scan pass A. In-place: read gate pack(a,b), write pack(S,PP).
// ---------------------------------------------------------------------------
__global__ __launch_bounds__(256) void k4a(
    unsigned int* __restrict__ ABF, unsigned int* __restrict__ ABB,
    float* __restrict__ Scar, float* __restrict__ Pcar, int nb)
{
    int g = blockIdx.x*256 + threadIdx.x;
    int col   = g & (H_-1);
    int chunk = (g >> 9) & (CH_-1);
    int rest  = g >> 13;
    int bb    = rest % nb;
    int dir   = rest / nb;
    unsigned int* AB = dir ? ABB : ABF;
    size_t base = (size_t)bb * L_ * H_ + col;
    float h = 0.f, pp = 1.f;
    if (dir == 0) {
        int lo = chunk * CL_;
        for (int p = 0; p < CL_; p += 8) {
            unsigned int v[8];
            #pragma unroll
            for (int j = 0; j < 8; j++) v[j] = AB[base + (size_t)(lo+p+j)*H_];
            #pragma unroll
            for (int j = 0; j < 8; j++) {
                size_t idx = base + (size_t)(lo+p+j)*H_;
                float av = b2f((unsigned short)(v[j] & 0xffffu));
                float bv = b2f((unsigned short)(v[j] >> 16));
                AB[idx] = (unsigned int)f2b(h) | ((unsigned int)f2b(pp) << 16);
                h = fmaf(av, h, bv);
                pp *= av;
            }
        }
    } else {
        int hi = chunk * CL_ + CL_ - 1;
        for (int p = 0; p < CL_; p += 8) {
            unsigned int v[8];
            #pragma unroll
            for (int j = 0; j < 8; j++) v[j] = AB[base + (size_t)(hi-p-j)*H_];
            #pragma unroll
            for (int j = 0; j < 8; j++) {
                size_t idx = base + (size_t)(hi-p-j)*H_;
                float av = b2f((unsigned short)(v[j] & 0xffffu));
                float bv = b2f((unsigned short)(v[j] >> 16));
                AB[idx] = (unsigned int)f2b(h) | ((unsigned int)f2b(pp) << 16);
                h = fmaf(av, h, bv);
                pp *= av;
            }
        }
    }
    int ci = ((dir*nb + bb)*CH_ + chunk)*H_ + col;
    Scar[ci] = h; Pcar[ci] = pp;
}

// K4b: chain carries across chunks.
__global__ __launch_bounds__(256) void k4b(
    const float* __restrict__ Scar, const float* __restrict__ Pcar,
    float* __restrict__ Hstart, int nb)
{
    int g = blockIdx.x*256 + threadIdx.x;
    int col  = g & (H_-1);
    int rest = g >> 9;
    int bb   = rest % nb;
    int dir  = rest / nb;
    int baseci = (dir*nb + bb)*CH_;
    float h = 0.f;
    if (dir == 0) {
        for (int c = 0; c < CH_; c++) {
            int ci = (baseci + c)*H_ + col;
            Hstart[ci] = h;
            h = Scar[ci] + Pcar[ci]*h;
        }
    } else {
        for (int c = CH_-1; c >= 0; c--) {
            int ci = (baseci + c)*H_ + col;
            Hstart[ci] = h;
            h = Scar[ci] + Pcar[ci]*h;
        }
    }
}

// K4c: h_out = S + PP*Hstart (elementwise), bf16 out.
__global__ __launch_bounds__(256) void k4c(
    const unsigned int* __restrict__ SPF, const unsigned int* __restrict__ SPB,
    const float* __restrict__ Hstart,
    unsigned short* __restrict__ hF, unsigned short* __restrict__ hB, int nb)
{
    int g = blockIdx.x*256 + threadIdx.x;
    int col   = g & (H_-1);
    int chunk = (g >> 9) & (CH_-1);
    int rest  = g >> 13;
    int bb    = rest % nb;
    int dir   = rest / nb;
    const unsigned int* SP = dir ? SPB : SPF;
    unsigned short* hout = dir ? hB : hF;
    size_t base = (size_t)bb * L_ * H_ + col;
    float h0 = Hstart[((dir*nb + bb)*CH_ + chunk)*H_ + col];
    int lo = chunk * CL_;
    for (int p = 0; p < CL_; p += 8) {
        unsigned int v[8];
        #pragma unroll
        for (int j = 0; j < 8; j++) v[j] = SP[base + (size_t)(lo+p+j)*H_];
        #pragma unroll
        for (int j = 0; j < 8; j++) {
            float S  = b2f((unsigned short)(v[j] & 0xffffu));
            float PP = b2f((unsigned short)(v[j] >> 16));
            hout[base + (size_t)(lo+p+j)*H_] = f2b(fmaf(PP, h0, S));
        }
    }
}

// ---------------------------------------------------------------------------
// K5 fused: LN(1032)+affine+time_scale -> LDS bf16 [32][KSTR_], then
// head GEMM (MFMA, barrier-free K-loop): A-frags from LDS, B-frags straight
// from global (one 16B load per frag), gelu*Wg2 + shfl row-reduce epilogue.
// 4 waves, wave = 64-col slice of N=256. Grid = rows/32.
// ---------------------------------------------------------------------------
__global__ __launch_bounds__(256) void k5_fused(
    const unsigned short* __restrict__ hf, const unsigned short* __restrict__ hb,
    const float* __restrict__ tenc,
    const float* __restrict__ ln_g, const float* __restrict__ ln_b,
    const float* __restrict__ tsp,
    const unsigned short* __restrict__ Wg1T,  // [256][1056] bf16
    const float* __restrict__ bg1, const float* __restrict__ Wg2,
    const float* __restrict__ bg2,
    float* __restrict__ out)
{
    __shared__ __align__(16) unsigned short A[32*KSTR_];   // 68 KB
    __shared__ float red[4][32];
    int tid = threadIdx.x, lane = tid & 63, wv = tid >> 6;
    int kg = lane >> 4, lr = lane & 15;
    int row0 = blockIdx.x * 32;
    float ts = tsp[0];

    // ---- LN phase: wave wv handles rows wv*8 .. wv*8+7 ----
    int c0 = lane*8;
    float4 g0a = *(const float4*)&ln_g[c0];
    float4 g0b = *(const float4*)&ln_g[c0+4];
    float4 b0a = *(const float4*)&ln_b[c0];
    float4 b0b = *(const float4*)&ln_b[c0+4];
    float4 g1a = *(const float4*)&ln_g[H_+c0];
    float4 g1b = *(const float4*)&ln_g[H_+c0+4];
    float4 b1a = *(const float4*)&ln_b[H_+c0];
    float4 b1b = *(const float4*)&ln_b[H_+c0+4];
    float gf[8] = {g0a.x,g0a.y,g0a.z,g0a.w,g0b.x,g0b.y,g0b.z,g0b.w};
    float bf_[8] = {b0a.x,b0a.y,b0a.z,b0a.w,b0b.x,b0b.y,b0b.z,b0b.w};
    float gb_[8] = {g1a.x,g1a.y,g1a.z,g1a.w,g1b.x,g1b.y,g1b.z,g1b.w};
    float bb_[8] = {b1a.x,b1a.y,b1a.z,b1a.w,b1b.x,b1b.y,b1b.z,b1b.w};
    float gt = 0.f, bt = 0.f;
    if (lane < NT_) { gt = ln_g[2*H_+lane]; bt = ln_b[2*H_+lane]; }

    #pragma unroll
    for (int i = 0; i < 8; i++) {
        int r = wv*8 + i;
        size_t row = (size_t)row0 + r;
        uint4 uf = *(const uint4*)&hf[row*H_ + c0];
        uint4 ub = *(const uint4*)&hb[row*H_ + c0];
        const unsigned short* pf = (const unsigned short*)&uf;
        const unsigned short* pb = (const unsigned short*)&ub;
        float fv[8], bv[8];
        float S = 0.f, Q = 0.f;
        #pragma unroll
        for (int j = 0; j < 8; j++) {
            fv[j] = b2f(pf[j]); S += fv[j]; Q += fv[j]*fv[j];
            bv[j] = b2f(pb[j]); S += bv[j]; Q += bv[j]*bv[j];
        }
        float tv = 0.f;
        if (lane < NT_) { tv = tenc[row*NT_ + lane]; S += tv; Q += tv*tv; }
        #pragma unroll
        for (int off = 32; off > 0; off >>= 1) {
            S += __shfl_xor(S, off, 64);
            Q += __shfl_xor(Q, off, 64);
        }
        float mu = S * (1.f/1032.f);
        float rs = rsqrtf(Q * (1.f/1032.f) - mu*mu + 1e-5f);
        unsigned short o[8];
        #pragma unroll
        for (int j = 0; j < 8; j++)
            o[j] = f2b((fv[j]-mu)*rs*gf[j] + bf_[j]);
        *(uint4*)&A[r*KSTR_ + c0] = *(const uint4*)o;
        #pragma unroll
        for (int j = 0; j < 8; j++)
            o[j] = f2b((bv[j]-mu)*rs*gb_[j] + bb_[j]);
        *(uint4*)&A[r*KSTR_ + H_ + c0] = *(const uint4*)o;
        if (lane < NT_) {
            A[r*KSTR_ + 2*H_ + lane] = f2b(((tv-mu)*rs*gt + bt) * ts);
        } else if (lane < 32) {
            A[r*KSTR_ + OUT_ + (lane-8)] = 0;
        }
    }
    __syncthreads();

    // ---- GEMM phase (no barriers): acc[m][n], m=2 (rows 16*m+..), n=4 ----
    f32x4 acc[2][4];
    #pragma unroll
    for (int m = 0; m < 2; m++)
        #pragma unroll
        for (int n = 0; n < 4; n++) acc[m][n] = (f32x4){0.f,0.f,0.f,0.f};

    const unsigned short* wbase = Wg1T + (size_t)(wv*64 + lr)*KPAD_ + kg*8;
    for (int k0 = 0; k0 < KPAD_; k0 += 32) {
        bf16x8 bfv[4];
        #pragma unroll
        for (int n = 0; n < 4; n++)
            bfv[n] = *(const bf16x8*)&wbase[(size_t)n*16*KPAD_ + k0];
        bf16x8 af0 = *(const bf16x8*)&A[lr*KSTR_ + k0 + kg*8];
        bf16x8 af1 = *(const bf16x8*)&A[(16+lr)*KSTR_ + k0 + kg*8];
        #pragma unroll
        for (int n = 0; n < 4; n++) {
            acc[0][n] = __builtin_amdgcn_mfma_f32_16x16x32_bf16(af0, bfv[n], acc[0][n], 0, 0, 0);
            acc[1][n] = __builtin_amdgcn_mfma_f32_16x16x32_bf16(af1, bfv[n], acc[1][n], 0, 0, 0);
        }
    }

    // ---- epilogue: gelu + *Wg2, reduce over cols ----
    float rsum[2][4] = {{0.f,0.f,0.f,0.f},{0.f,0.f,0.f,0.f}};
    #pragma unroll
    for (int n = 0; n < 4; n++) {
        int colg = wv*64 + n*16 + lr;
        float bgv = bg1[colg], w2v = Wg2[colg];
        #pragma unroll
        for (int m = 0; m < 2; m++)
            #pragma unroll
            for (int r = 0; r < 4; r++) {
                float gv = acc[m][n][r] + bgv;
                gv = 0.5f*gv*(1.f + erff(gv*0.70710678118654752f));
                rsum[m][r] = fmaf(gv, w2v, rsum[m][r]);
            }
    }
    #pragma unroll
    for (int off = 1; off < 16; off <<= 1)
        #pragma unroll
        for (int m = 0; m < 2; m++)
            #pragma unroll
            for (int r = 0; r < 4; r++)
                rsum[m][r] += __shfl_xor(rsum[m][r], off, 64);
    if (lr == 0) {
        #pragma unroll
        for (int m = 0; m < 2; m++)
            #pragma unroll
            for (int r = 0; r < 4; r++)
                red[wv][m*16 + kg*4 + r] = rsum[m][r];
    }
    __syncthreads();
    if (tid < 32)
        out[row0 + tid] = red[0][tid] + red[1][tid] + red[2][tid] + red[3][tid] + bg2[0];
}

// ---------------------------------------------------------------------------
extern "C" void kernel_launch(void* const* d_in, const int* in_sizes, int n_in,
                              void* d_out, int out_size, void* d_ws, size_t ws_size,
                              hipStream_t stream)
{
    const float* x    = (const float*)d_in[0];
    const float* t    = (const float*)d_in[1];
    const float* Wt1  = (const float*)d_in[2];
    const float* bt1  = (const float*)d_in[3];
    const float* Wt2  = (const float*)d_in[4];
    const float* bt2  = (const float*)d_in[5];
    const float* Wpf  = (const float*)d_in[6];
    const float* bpf  = (const float*)d_in[7];
    const float* Wpb  = (const float*)d_in[8];
    const float* bpb  = (const float*)d_in[9];
    const float* Wzf  = (const float*)d_in[10];
    const float* bzf  = (const float*)d_in[11];
    const float* Whf  = (const float*)d_in[12];
    const float* bhf  = (const float*)d_in[13];
    const float* Wzb  = (const float*)d_in[14];
    const float* bzb  = (const float*)d_in[15];
    const float* Whb  = (const float*)d_in[16];
    const float* bhb  = (const float*)d_in[17];
    const float* ln_g = (const float*)d_in[18];
    const float* ln_b = (const float*)d_in[19];
    const float* tsc  = (const float*)d_in[20];
    const float* Wg1  = (const float*)d_in[21];
    const float* bg1  = (const float*)d_in[22];
    const float* Wg2  = (const float*)d_in[23];
    const float* bg2  = (const float*)d_in[24];
    float* out = (float*)d_out;

    char* p = (char*)d_ws;
    auto carve = [&](size_t bytes) -> char* {
        char* q = p; p += (bytes + 255) & ~(size_t)255; return q;
    };

    unsigned short* WzTf = (unsigned short*)carve((size_t)H_*H_*2);
    unsigned short* WhTf = (unsigned short*)carve((size_t)H_*H_*2);
    unsigned short* WzTb = (unsigned short*)carve((size_t)H_*H_*2);
    unsigned short* WhTb = (unsigned short*)carve((size_t)H_*H_*2);
    unsigned short* Wg1T = (unsigned short*)carve((size_t)HEAD_*KPAD_*2);

    const size_t perBatch = (size_t)L_*H_*2*2
                          + (size_t)L_*H_*4*2
                          + (size_t)L_*NT_*4
                          + (size_t)CH_*H_*4*3*2;
    size_t fixedUsed = (size_t)(p - (char*)d_ws) + 64*1024;
    int NB = B_;
    while (NB > 1 && fixedUsed + (size_t)NB*perBatch > ws_size) NB >>= 1;

    unsigned short* inpF = (unsigned short*)carve((size_t)NB*L_*H_*2);
    unsigned short* inpB = (unsigned short*)carve((size_t)NB*L_*H_*2);
    unsigned int*   ABF  = (unsigned int*)carve((size_t)NB*L_*H_*4);
    unsigned int*   ABB  = (unsigned int*)carve((size_t)NB*L_*H_*4);
    float* tenc   = (float*)carve((size_t)NB*L_*NT_*4);
    float* Scar   = (float*)carve((size_t)2*NB*CH_*H_*4);
    float* Pcar   = (float*)carve((size_t)2*NB*CH_*H_*4);
    float* Hstart = (float*)carve((size_t)2*NB*CH_*H_*4);

    {
        dim3 g(H_/32, H_/32);
        kT<<<g, 256, 0, stream>>>(Wzf, WzTf, H_, H_, H_);
        kT<<<g, 256, 0, stream>>>(Whf, WhTf, H_, H_, H_);
        kT<<<g, 256, 0, stream>>>(Wzb, WzTb, H_, H_, H_);
        kT<<<g, 256, 0, stream>>>(Whb, WhTb, H_, H_, H_);
        dim3 gg(HEAD_/32, KPAD_/32);
        kT<<<gg, 256, 0, stream>>>(Wg1, Wg1T, OUT_, HEAD_, KPAD_);
    }

    for (int b0 = 0; b0 < B_; b0 += NB) {
        int rows = NB * L_;
        k1_tenc_inp<<<rows, 256, 0, stream>>>(
            x + (size_t)b0*L_*2, t + (size_t)b0*L_,
            Wt1, bt1, Wt2, bt2, Wpf, bpf, Wpb, bpb,
            tenc, inpF, inpB);

        dim3 g3(rows/128, H_/64);
        k3_mfma<<<g3, 256, 0, stream>>>(inpF, WzTf, WhTf, bzf, bhf, ABF);
        k3_mfma<<<g3, 256, 0, stream>>>(inpB, WzTb, WhTb, bzb, bhb, ABB);

        int scanThreads = 2*NB*H_*CH_;
        k4a<<<scanThreads/256, 256, 0, stream>>>(ABF, ABB, Scar, Pcar, NB);
        k4b<<<(2*NB*H_)/256, 256, 0, stream>>>(Scar, Pcar, Hstart, NB);
        k4c<<<scanThreads/256, 256, 0, stream>>>(ABF, ABB, Hstart, inpF, inpB, NB);

        k5_fused<<<rows/32, 256, 0, stream>>>(
            inpF, inpB, tenc, ln_g, ln_b, tsc,
            Wg1T, bg1, Wg2, bg2, out + (size_t)b0*L_);
    }
}